// Round 2
// baseline (357.784 us; speedup 1.0000x reference)
//
#include <hip/hip_runtime.h>
#include <hip/hip_bf16.h>

#define D_FEAT 64

// Kernel 1: out = input (vectorized float4 copy; also initializes poisoned d_out)
__global__ void mp_copy_kernel(const float4* __restrict__ in,
                               float4* __restrict__ out, int n4) {
    int i = blockIdx.x * blockDim.x + threadIdx.x;
    if (i < n4) out[i] = in[i];
}

// Kernel 2: per (edge, feature) scatter-add.
// tid>>6 = edge index, tid&63 = feature lane. All 64 lanes of a wave handle
// one edge: coalesced 256B read of the source row, 64 float atomics to dst row.
__global__ void mp_scatter_kernel(const float* __restrict__ input,
                                  const float* __restrict__ ew,
                                  const int* __restrict__ esrc,
                                  const int* __restrict__ edst,
                                  float* __restrict__ out, int n_edges) {
    int tid = blockIdx.x * blockDim.x + threadIdx.x;
    int e = tid >> 6;
    if (e >= n_edges) return;
    int lane = tid & 63;
    int s = esrc[e];
    int d = edst[e];
    float w = ew[e];
    float v = input[(long long)s * D_FEAT + lane] * w;
    atomicAdd(&out[(long long)d * D_FEAT + lane], v);
}

extern "C" void kernel_launch(void* const* d_in, const int* in_sizes, int n_in,
                              void* d_out, int out_size, void* d_ws, size_t ws_size,
                              hipStream_t stream) {
    const float* input = (const float*)d_in[0];
    const float* ew    = (const float*)d_in[1];
    const int* esrc    = (const int*)d_in[2];   // harness passes integer inputs as int32
    const int* edst    = (const int*)d_in[3];
    float* out = (float*)d_out;

    int n_nodes = in_sizes[0] / D_FEAT;   // 100000
    int n_edges = in_sizes[1];            // 1600000

    // out = input
    int n4 = (n_nodes * D_FEAT) / 4;      // multiple of 4 (D_FEAT=64)
    int cblk = 256;
    int cgrid = (n4 + cblk - 1) / cblk;
    mp_copy_kernel<<<cgrid, cblk, 0, stream>>>((const float4*)input, (float4*)out, n4);

    // scatter-add edges: 64 lanes per edge
    long long total = (long long)n_edges * 64;
    int sblk = 256;
    long long sgrid = (total + sblk - 1) / sblk;
    mp_scatter_kernel<<<(int)sgrid, sblk, 0, stream>>>(input, ew, esrc, edst, out, n_edges);
}